// Round 3
// baseline (1024.666 us; speedup 1.0000x reference)
//
#include <hip/hip_runtime.h>

// ---------------------------------------------------------------------------
// LoRA QKV: out_p = x @ (W_p + B_p @ A_p)^T  for p in {q,k,v}
// M = 8192, N = 4096 per proj (x3), K = 4096.
// Fold LoRA into weights (exact), convert to bf16, fused 3-proj GEMM using
// the m201-faithful 256x256 8-phase quadrant schedule:
//   T2 LDS XOR-swizzle + T3/T4 counted vmcnt/lgkmcnt + T5 setprio.
// ---------------------------------------------------------------------------

typedef __bf16 bf16x8 __attribute__((ext_vector_type(8)));
typedef float f32x4 __attribute__((ext_vector_type(4)));

#define GLL16(g, l)                                                        \
  __builtin_amdgcn_global_load_lds(                                        \
      (const __attribute__((address_space(1))) unsigned int*)(g),          \
      (__attribute__((address_space(3))) unsigned int*)(l), 16, 0, 0)

#define BAR()                                                              \
  {                                                                        \
    __builtin_amdgcn_sched_barrier(0);                                     \
    __builtin_amdgcn_s_barrier();                                          \
  }
#define WLG(n)                                                             \
  {                                                                        \
    asm volatile("s_waitcnt lgkmcnt(" #n ")" ::: "memory");                \
    __builtin_amdgcn_sched_barrier(0);                                     \
  }
#define WVM(n) asm volatile("s_waitcnt vmcnt(" #n ")" ::: "memory")

#define LDV(p) (*reinterpret_cast<const bf16x8*>(p))

// read 4 A-frags (m = MH*4 .. MH*4+3) at k-swizzle swk into dst
#define RD_A4(dst, base, MH, swk)                                          \
  _Pragma("unroll") for (int mq = 0; mq < 4; ++mq) dst[(MH)*4 + mq] =      \
      LDV((base) + ((MH)*4 + mq) * 1024 + (swk));
// read 2 B-frags (n = NH*2 .. NH*2+1)
#define RD_B2(dst, base, NH, swk)                                          \
  _Pragma("unroll") for (int nq = 0; nq < 2; ++nq) dst[(NH)*2 + nq] =      \
      LDV((base) + ((NH)*2 + nq) * 1024 + (swk));

// 8 MFMAs: quadrant (MH, NH), one k-substep (array choice), setprio-wrapped
#define MF8(AARR, BARR, MH, NH)                                            \
  {                                                                        \
    __builtin_amdgcn_s_setprio(1);                                         \
    _Pragma("unroll") for (int mm = 0; mm < 4; ++mm)                       \
        _Pragma("unroll") for (int nn = 0; nn < 2; ++nn)                   \
            acc[(MH)*4 + mm][(NH)*2 + nn] =                                \
                __builtin_amdgcn_mfma_f32_16x16x32_bf16(                   \
                    AARR[(MH)*4 + mm], BARR[(NH)*2 + nn],                  \
                    acc[(MH)*4 + mm][(NH)*2 + nn], 0, 0, 0);               \
    __builtin_amdgcn_s_setprio(0);                                         \
  }

// stage one 8KB chunk (chunk j) of A/B tile into LDS dbuf db, K elem-offset ko
#define STG_A(db, j, ko)                                                   \
  GLL16(sa + (size_t)(j)*262144 + (ko),                                    \
        (char*)smem + (db)*65536 + (j)*8192 + tid * 16)
#define STG_B(db, j, ko)                                                   \
  GLL16(sb + (size_t)(j)*262144 + (ko),                                    \
        (char*)smem + (db)*65536 + 32768 + (j)*8192 + tid * 16)

__device__ __forceinline__ unsigned int f2b(float f) {
  unsigned int u = __builtin_bit_cast(unsigned int, f);
  u += 0x7FFFu + ((u >> 16) & 1u);
  return u >> 16;
}

// ---------------------------------------------------------------------------
// Kernel 1: convert x (fp32) -> bf16
// ---------------------------------------------------------------------------
__global__ void cvt_x_kernel(const float* __restrict__ x,
                             unsigned short* __restrict__ xb, long n8) {
  long i = (long)blockIdx.x * blockDim.x + threadIdx.x;
  if (i >= n8) return;
  const float4* xp = reinterpret_cast<const float4*>(x) + 2 * i;
  float4 v0 = xp[0];
  float4 v1 = xp[1];
  uint4 o;
  o.x = f2b(v0.x) | (f2b(v0.y) << 16);
  o.y = f2b(v0.z) | (f2b(v0.w) << 16);
  o.z = f2b(v1.x) | (f2b(v1.y) << 16);
  o.w = f2b(v1.z) | (f2b(v1.w) << 16);
  reinterpret_cast<uint4*>(xb)[i] = o;
}

// ---------------------------------------------------------------------------
// Kernel 2: W' = W + Bm @ A  (rank-16), fp32 accum, bf16 out
// ---------------------------------------------------------------------------
__global__ void fold_w_kernel(const float* __restrict__ W,
                              const float* __restrict__ Amat,
                              const float* __restrict__ Bmat,
                              unsigned short* __restrict__ Wb) {
  int gi = blockIdx.x * 256 + threadIdx.x;
  int d0 = (gi & 511) * 8;
  int h = gi >> 9;
  const float4* wp = reinterpret_cast<const float4*>(W + (size_t)h * 4096 + d0);
  float4 w0 = wp[0], w1 = wp[1];
  float acc[8] = {w0.x, w0.y, w0.z, w0.w, w1.x, w1.y, w1.z, w1.w};
  const float* bh = Bmat + h * 16;
#pragma unroll
  for (int r = 0; r < 16; ++r) {
    float bv = bh[r];
    const float4* ap =
        reinterpret_cast<const float4*>(Amat + (size_t)r * 4096 + d0);
    float4 a0 = ap[0], a1 = ap[1];
    acc[0] += bv * a0.x; acc[1] += bv * a0.y;
    acc[2] += bv * a0.z; acc[3] += bv * a0.w;
    acc[4] += bv * a1.x; acc[5] += bv * a1.y;
    acc[6] += bv * a1.z; acc[7] += bv * a1.w;
  }
  uint4 o;
  o.x = f2b(acc[0]) | (f2b(acc[1]) << 16);
  o.y = f2b(acc[2]) | (f2b(acc[3]) << 16);
  o.z = f2b(acc[4]) | (f2b(acc[5]) << 16);
  o.w = f2b(acc[6]) | (f2b(acc[7]) << 16);
  reinterpret_cast<uint4*>(Wb)[gi] = o;
}

// ---------------------------------------------------------------------------
// Kernel 3: 256x256-tile 8-phase quadrant GEMM.
//   C[M, N*3] = Xb[M,K] @ Wb[3][N,K]^T
// 512 threads = 8 waves (2M x 4N), per-wave C = 128x64. BK=64 (2 x K32).
// LDS 128 KiB: [A0|B0][A1|B1] double-buffered K-tiles, 16B-slot XOR swizzle
// (slot s of row r holds global slot s^(r&7)), applied on the global SOURCE
// (global_load_lds writes linearly) and on the ds_read address.
// 8 phases / 2 K-tiles; each phase: {ds_reads (12/8/4/0) | 2 gloads} -> bar
// -> counted lgkmcnt -> 8 MFMA -> lgkmcnt(0) -> 8 MFMA -> bar.
// vmcnt(2) only at P4/P8. Stage windows race-free by construction:
//   buf0 reads fully drained at P3's lgkmcnt(0); buf0-next staged P4-P7.
//   buf1 reads drained at P7; buf1-next staged P8 + P1'-P3' (gated i>0;
//   prologue stages tiles 0 and 1 fully).
// ---------------------------------------------------------------------------
__global__ __launch_bounds__(512, 2) void gemm_kernel(
    const unsigned short* __restrict__ Xb,
    const unsigned short* __restrict__ Wb, float* __restrict__ out) {
  __shared__ unsigned short smem[65536];  // 128 KiB

  const int tid = threadIdx.x;
  const int lane = tid & 63;
  const int wid = tid >> 6;
  const int wm = wid >> 2;  // 0..1
  const int wn = wid & 3;   // 0..3

  int bid = blockIdx.x;                    // 1536 = 3 proj * 32 brow * 16 bcol
  int swz = (bid & 7) * 192 + (bid >> 3);  // bijective XCD swizzle
  int p = swz >> 9;
  int r = swz & 511;
  int brow = r >> 4;  // 0..31
  int bcol = r & 15;  // 0..15

  const unsigned short* GA = Xb + (size_t)brow * 256 * 4096;
  const unsigned short* GB =
      Wb + (size_t)p * 16777216UL + (size_t)bcol * 256 * 4096;

  // staging: thread covers row (tid>>3) of each 64-row chunk, 16B slot tid&7;
  // source slot pre-swizzled so LDS[r][s] holds global[r][s^(r&7)]
  const int srow = tid >> 3;
  const int sslot = (tid & 7) ^ ((tid >> 3) & 7);
  const unsigned short* sa = GA + (size_t)srow * 4096 + sslot * 8;
  const unsigned short* sb = GB + (size_t)srow * 4096 + sslot * 8;

  // fragment-read bases (element units), swizzled k-slot offsets
  const int lrow = lane & 15;
  const int g = lane >> 4;  // 0..3
  const int swk0 = (g ^ (lane & 7)) * 8;
  const int swk1 = ((4 + g) ^ (lane & 7)) * 8;
  const __bf16* sm = (const __bf16*)smem;
  const __bf16* arA0 = sm + (wm * 128 + lrow) * 64;
  const __bf16* arB0 = sm + 16384 + (wn * 64 + lrow) * 64;
  const __bf16* arA1 = arA0 + 32768;
  const __bf16* arB1 = arB0 + 32768;

  f32x4 acc[8][4];
#pragma unroll
  for (int m = 0; m < 8; ++m)
#pragma unroll
    for (int n = 0; n < 4; ++n) acc[m][n] = {0.f, 0.f, 0.f, 0.f};

  // prologue: stage tile0 -> buf0, tile1 -> buf1 (8 loads each)
#pragma unroll
  for (int j = 0; j < 4; ++j) {
    STG_A(0, j, 0);
    STG_B(0, j, 0);
  }
#pragma unroll
  for (int j = 0; j < 4; ++j) {
    STG_A(1, j, 64);
    STG_B(1, j, 64);
  }
  WVM(8);  // tile0 landed; tile1's 8 loads stay in flight
  BAR();

  bf16x8 aK0[8], aK1[8], bK0[4], bK1[4];

  for (int i = 0; i < 32; ++i) {
    const bool st = (i < 31);
    const bool sp = (i > 0);
    const size_t ko1c = (size_t)(2 * i + 1) * 64;  // buf1 current tile
    const size_t ko0n = (size_t)(2 * i + 2) * 64;  // buf0 next tile
    const size_t ko1n = (size_t)(2 * i + 3) * 64;  // buf1 next tile

    // ================= buf0 (tile 2i) =================
    // P1: quadrant (0,0); reads 12
    RD_A4(aK0, arA0, 0, swk0);
    RD_B2(bK0, arB0, 0, swk0);
    RD_A4(aK1, arA0, 0, swk1);
    RD_B2(bK1, arB0, 0, swk1);
    if (sp) { STG_A(1, 1, ko1c); STG_B(1, 1, ko1c); }
    BAR();
    WLG(6);
    MF8(aK0, bK0, 0, 0);
    WLG(0);
    MF8(aK1, bK1, 0, 0);
    BAR();
    // P2: quadrant (1,0); reads 8
    RD_A4(aK0, arA0, 1, swk0);
    RD_A4(aK1, arA0, 1, swk1);
    if (sp) { STG_A(1, 2, ko1c); STG_B(1, 2, ko1c); }
    BAR();
    WLG(4);
    MF8(aK0, bK0, 1, 0);
    WLG(0);
    MF8(aK1, bK1, 1, 0);
    BAR();
    // P3: quadrant (0,1); reads 4 — buf0 fully read after this drain
    RD_B2(bK0, arB0, 1, swk0);
    RD_B2(bK1, arB0, 1, swk1);
    if (sp) { STG_A(1, 3, ko1c); STG_B(1, 3, ko1c); }
    BAR();
    WLG(2);
    MF8(aK0, bK0, 0, 1);
    WLG(0);
    MF8(aK1, bK1, 0, 1);
    BAR();
    // P4: quadrant (1,1); no reads; vmcnt(2) drains buf1's current tile
    if (st) {
      STG_A(0, 0, ko0n);
      STG_B(0, 0, ko0n);
      WVM(2);
    } else {
      WVM(0);
    }
    BAR();
    MF8(aK0, bK0, 1, 1);
    MF8(aK1, bK1, 1, 1);
    BAR();

    // ================= buf1 (tile 2i+1) =================
    // P5: quadrant (0,0)
    RD_A4(aK0, arA1, 0, swk0);
    RD_B2(bK0, arB1, 0, swk0);
    RD_A4(aK1, arA1, 0, swk1);
    RD_B2(bK1, arB1, 0, swk1);
    if (st) { STG_A(0, 1, ko0n); STG_B(0, 1, ko0n); }
    BAR();
    WLG(6);
    MF8(aK0, bK0, 0, 0);
    WLG(0);
    MF8(aK1, bK1, 0, 0);
    BAR();
    // P6: quadrant (1,0)
    RD_A4(aK0, arA1, 1, swk0);
    RD_A4(aK1, arA1, 1, swk1);
    if (st) { STG_A(0, 2, ko0n); STG_B(0, 2, ko0n); }
    BAR();
    WLG(4);
    MF8(aK0, bK0, 1, 0);
    WLG(0);
    MF8(aK1, bK1, 1, 0);
    BAR();
    // P7: quadrant (0,1) — buf1 fully read after this drain
    RD_B2(bK0, arB1, 1, swk0);
    RD_B2(bK1, arB1, 1, swk1);
    if (st) { STG_A(0, 3, ko0n); STG_B(0, 3, ko0n); }
    BAR();
    WLG(2);
    MF8(aK0, bK0, 0, 1);
    WLG(0);
    MF8(aK1, bK1, 0, 1);
    BAR();
    // P8: quadrant (1,1); vmcnt(2) drains buf0's next tile
    if (st) {
      STG_A(1, 0, ko1n);
      STG_B(1, 0, ko1n);
      WVM(2);
    }
    BAR();
    MF8(aK0, bK0, 1, 1);
    MF8(aK1, bK1, 1, 1);
    BAR();
  }

  // epilogue: C/D layout col = lane&15, row = (lane>>4)*4 + q
  float* Cp = out + (size_t)p * 33554432UL +
              ((size_t)(brow * 256 + wm * 128 + g * 4)) * 4096 +
              (bcol * 256 + wn * 64 + lrow);
#pragma unroll
  for (int m = 0; m < 8; ++m)
#pragma unroll
    for (int q = 0; q < 4; ++q) {
      float* rp = Cp + (size_t)(m * 16 + q) * 4096;
#pragma unroll
      for (int n = 0; n < 4; ++n) rp[n * 16] = acc[m][n][q];
    }
}

// ---------------------------------------------------------------------------
extern "C" void kernel_launch(void* const* d_in, const int* in_sizes, int n_in,
                              void* d_out, int out_size, void* d_ws,
                              size_t ws_size, hipStream_t stream) {
  const float* x = (const float*)d_in[0];
  const float* wq = (const float*)d_in[1];
  const float* wk = (const float*)d_in[2];
  const float* wv = (const float*)d_in[3];
  const float* qa = (const float*)d_in[4];
  const float* qb = (const float*)d_in[5];
  const float* ka = (const float*)d_in[6];
  const float* kb = (const float*)d_in[7];
  const float* va = (const float*)d_in[8];
  const float* vb = (const float*)d_in[9];

  unsigned short* xb = (unsigned short*)d_ws;  // 67 MB
  unsigned short* wb = xb + 8192UL * 4096UL;   // 100 MB

  cvt_x_kernel<<<16384, 256, 0, stream>>>(x, xb, 8192L * 4096 / 8);
  fold_w_kernel<<<8192, 256, 0, stream>>>(wq, qa, qb, wb);
  fold_w_kernel<<<8192, 256, 0, stream>>>(wk, ka, kb, wb + 16777216UL);
  fold_w_kernel<<<8192, 256, 0, stream>>>(wv, va, vb, wb + 33554432UL);
  gemm_kernel<<<1536, 512, 0, stream>>>(xb, wb, (float*)d_out);
}

// Round 4
// 914.462 us; speedup vs baseline: 1.1205x; 1.1205x over previous
//
#include <hip/hip_runtime.h>

// ---------------------------------------------------------------------------
// LoRA QKV: out_p = x @ (W_p + B_p @ A_p)^T  for p in {q,k,v}
// M = 8192, N = 4096 per proj (x3), K = 4096.
// Fold LoRA into weights (exact), convert to bf16, fused 3-proj GEMM using
// the m201 256x256 8-phase schedule with half-tile staging and depth-3
// counted vmcnt (T2 swizzle + T3/T4 + T5 setprio).
// ---------------------------------------------------------------------------

typedef __bf16 bf16x8 __attribute__((ext_vector_type(8)));
typedef float f32x4 __attribute__((ext_vector_type(4)));

#define GLL16(g, l)                                                        \
  __builtin_amdgcn_global_load_lds(                                        \
      (const __attribute__((address_space(1))) unsigned int*)(g),          \
      (__attribute__((address_space(3))) unsigned int*)(l), 16, 0, 0)

#define BAR()                                                              \
  {                                                                        \
    __builtin_amdgcn_sched_barrier(0);                                     \
    __builtin_amdgcn_s_barrier();                                          \
  }
#define WLG(n) asm volatile("s_waitcnt lgkmcnt(" #n ")" ::: "memory")
#define WVM(n) asm volatile("s_waitcnt vmcnt(" #n ")" ::: "memory")

#define LDV(p) (*reinterpret_cast<const bf16x8*>(p))

// read 4 A-frags (m = M0..M0+3), both k-substeps, into dst[2][4]
#define RDA(dst, base, M0)                                                 \
  _Pragma("unroll") for (int mm = 0; mm < 4; ++mm) {                       \
    dst[0][mm] = LDV((base) + ((M0) + mm) * 1024 + swk0);                  \
    dst[1][mm] = LDV((base) + ((M0) + mm) * 1024 + swk1);                  \
  }
// read 2 B-frags (n = N0..N0+1), both k-substeps, into dst[2][2]
#define RDB(dst, base, N0)                                                 \
  _Pragma("unroll") for (int nn = 0; nn < 2; ++nn) {                       \
    dst[0][nn] = LDV((base) + ((N0) + nn) * 1024 + swk0);                  \
    dst[1][nn] = LDV((base) + ((N0) + nn) * 1024 + swk1);                  \
  }

// one C-quadrant x K=64: 16 MFMAs, setprio-wrapped (T5)
#define MFQ(AQ, BQ, MB, NB)                                                \
  {                                                                        \
    __builtin_amdgcn_s_setprio(1);                                         \
    _Pragma("unroll") for (int ks = 0; ks < 2; ++ks)                       \
        _Pragma("unroll") for (int mm = 0; mm < 4; ++mm)                   \
            _Pragma("unroll") for (int nn = 0; nn < 2; ++nn)               \
                acc[(MB) + mm][(NB) + nn] =                                \
                    __builtin_amdgcn_mfma_f32_16x16x32_bf16(               \
                        AQ[ks][mm], BQ[ks][nn], acc[(MB) + mm][(NB) + nn], \
                        0, 0, 0);                                          \
    __builtin_amdgcn_s_setprio(0);                                         \
  }

// stage one 16KB half-tile (2 loads/thread). h = row-half (0/1), ko = K elem.
#define STG_A(db, h, ko)                                                   \
  {                                                                        \
    GLL16(sa + (size_t)((h)*128) * 4096 + (ko),                            \
          (char*)smem + (db)*65536 + (h)*16384 + tid * 16);                \
    GLL16(sa + (size_t)((h)*128 + 64) * 4096 + (ko),                       \
          (char*)smem + (db)*65536 + (h)*16384 + 8192 + tid * 16);         \
  }
#define STG_B(db, h, ko)                                                   \
  {                                                                        \
    GLL16(sb + (size_t)((h)*128) * 4096 + (ko),                            \
          (char*)smem + (db)*65536 + 32768 + (h)*16384 + tid * 16);        \
    GLL16(sb + (size_t)((h)*128 + 64) * 4096 + (ko),                       \
          (char*)smem + (db)*65536 + 32768 + (h)*16384 + 8192 + tid * 16); \
  }

__device__ __forceinline__ unsigned int f2b(float f) {
  unsigned int u = __builtin_bit_cast(unsigned int, f);
  u += 0x7FFFu + ((u >> 16) & 1u);
  return u >> 16;
}

// ---------------------------------------------------------------------------
// Kernel 1: convert x (fp32) -> bf16
// ---------------------------------------------------------------------------
__global__ void cvt_x_kernel(const float* __restrict__ x,
                             unsigned short* __restrict__ xb, long n8) {
  long i = (long)blockIdx.x * blockDim.x + threadIdx.x;
  if (i >= n8) return;
  const float4* xp = reinterpret_cast<const float4*>(x) + 2 * i;
  float4 v0 = xp[0];
  float4 v1 = xp[1];
  uint4 o;
  o.x = f2b(v0.x) | (f2b(v0.y) << 16);
  o.y = f2b(v0.z) | (f2b(v0.w) << 16);
  o.z = f2b(v1.x) | (f2b(v1.y) << 16);
  o.w = f2b(v1.z) | (f2b(v1.w) << 16);
  reinterpret_cast<uint4*>(xb)[i] = o;
}

// ---------------------------------------------------------------------------
// Kernel 2: W' = W + Bm @ A  (rank-16), fp32 accum, bf16 out
// ---------------------------------------------------------------------------
__global__ void fold_w_kernel(const float* __restrict__ W,
                              const float* __restrict__ Amat,
                              const float* __restrict__ Bmat,
                              unsigned short* __restrict__ Wb) {
  int gi = blockIdx.x * 256 + threadIdx.x;
  int d0 = (gi & 511) * 8;
  int h = gi >> 9;
  const float4* wp = reinterpret_cast<const float4*>(W + (size_t)h * 4096 + d0);
  float4 w0 = wp[0], w1 = wp[1];
  float acc[8] = {w0.x, w0.y, w0.z, w0.w, w1.x, w1.y, w1.z, w1.w};
  const float* bh = Bmat + h * 16;
#pragma unroll
  for (int r = 0; r < 16; ++r) {
    float bv = bh[r];
    const float4* ap =
        reinterpret_cast<const float4*>(Amat + (size_t)r * 4096 + d0);
    float4 a0 = ap[0], a1 = ap[1];
    acc[0] += bv * a0.x; acc[1] += bv * a0.y;
    acc[2] += bv * a0.z; acc[3] += bv * a0.w;
    acc[4] += bv * a1.x; acc[5] += bv * a1.y;
    acc[6] += bv * a1.z; acc[7] += bv * a1.w;
  }
  uint4 o;
  o.x = f2b(acc[0]) | (f2b(acc[1]) << 16);
  o.y = f2b(acc[2]) | (f2b(acc[3]) << 16);
  o.z = f2b(acc[4]) | (f2b(acc[5]) << 16);
  o.w = f2b(acc[6]) | (f2b(acc[7]) << 16);
  reinterpret_cast<uint4*>(Wb)[gi] = o;
}

// ---------------------------------------------------------------------------
// Kernel 3: 256x256-tile 8-phase GEMM (m201 schedule).
//   C[M, N*3] = Xb[M,K] @ Wb[3][N,K]^T
// 512 threads = 8 waves (2M x 4N), wave tile 128x64. BK=64 (2 x K32).
// LDS 128 KiB = 2 dbuf x { A: 2 x 16KB row-halves | B: 2 x 16KB }.
// 16B-slot XOR swizzle (phys slot s of row r holds global slot s^(r&7));
// applied on global SOURCE (global_load_lds writes linearly) + read addr.
// Phase = { quadrant ds_reads (12/4/8/0) | 1 half-tile stage } -> barrier ->
// lgkmcnt(0) -> setprio(1) 16 MFMA setprio(0) -> barrier.
// Stage mapping (forced by vmcnt(6)@P4/P8 ledger):
//   P1: D1cur.A1 | P2: D0n.B0 | P3: D0n.B1 | P4: D0n.A0 +vm(6)
//   P5: D0n.A1   | P6: D1n.B0 | P7: D1n.B1 | P8: D1n.A0 +vm(6)
// Every buffer fully lands one barrier before first read (ledger-verified);
// all stage-issues are after the old content's read-drain (or same-phase
// after-reads, m201's validated pattern).
// ---------------------------------------------------------------------------
__global__ __launch_bounds__(512, 2) void gemm_kernel(
    const unsigned short* __restrict__ Xb,
    const unsigned short* __restrict__ Wb, float* __restrict__ out) {
  __shared__ unsigned short smem[65536];  // 128 KiB

  const int tid = threadIdx.x;
  const int lane = tid & 63;
  const int wid = tid >> 6;
  const int wm = wid >> 2;  // 0..1
  const int wn = wid & 3;   // 0..3

  int bid = blockIdx.x;                    // 1536 = 3 proj * 32 brow * 16 bcol
  int swz = (bid & 7) * 192 + (bid >> 3);  // bijective XCD swizzle
  int p = swz >> 9;
  int r = swz & 511;
  int brow = r >> 4;  // 0..31
  int bcol = r & 15;  // 0..15

  const unsigned short* GA = Xb + (size_t)brow * 256 * 4096;
  const unsigned short* GB =
      Wb + (size_t)p * 16777216UL + (size_t)bcol * 256 * 4096;

  // staging: thread covers row (tid>>3) of each 64-row block, 16B slot tid&7;
  // source slot pre-swizzled so LDS[r][s] holds global[r][s^(r&7)]
  const int srow = tid >> 3;
  const int sslot = (tid & 7) ^ (srow & 7);
  const unsigned short* sa = GA + (size_t)srow * 4096 + sslot * 8;
  const unsigned short* sb = GB + (size_t)srow * 4096 + sslot * 8;

  // fragment-read bases (element units), swizzled k-slot offsets
  const int lrow = lane & 15;
  const int g = lane >> 4;  // 0..3
  const int swk0 = (g ^ (lane & 7)) * 8;
  const int swk1 = ((4 + g) ^ (lane & 7)) * 8;
  const __bf16* sm = (const __bf16*)smem;
  // A: [db 32768][half 8192][row 64]; wave wm reads its own half
  const __bf16* arA0 = sm + wm * 8192 + lrow * 64;
  const __bf16* arB0 = sm + 16384 + (wn >> 1) * 8192 + ((wn & 1) * 64 + lrow) * 64;
  const __bf16* arA1 = arA0 + 32768;
  const __bf16* arB1 = arB0 + 32768;

  f32x4 acc[8][4];
#pragma unroll
  for (int m = 0; m < 8; ++m)
#pragma unroll
    for (int n = 0; n < 4; ++n) acc[m][n] = {0.f, 0.f, 0.f, 0.f};

  // prologue (half-tile order = ledger order h0..h3 = B0,B1,A0,A1):
  STG_B(0, 0, 0); STG_B(0, 1, 0); STG_A(0, 0, 0); STG_A(0, 1, 0);
  WVM(4);  // t0.B0,B1 landed
  STG_B(1, 0, 64); STG_B(1, 1, 64); STG_A(1, 0, 64);
  WVM(6);  // t0.A0,A1 landed -> tile0 complete; 6 of tile1 in flight
  BAR();

  bf16x8 aLo[2][4], aHi[2][4], bLo[2][2], bHi[2][2];

  for (int i = 0; i < 32; ++i) {
    const bool st = (i < 31);
    const size_t koD1 = (size_t)(2 * i + 1) * 64;  // current D1 tile
    const size_t koN0 = (size_t)(2 * i + 2) * 64;  // next D0 tile
    const size_t koN1 = (size_t)(2 * i + 3) * 64;  // next D1 tile

    // ================= D0 (tile 2i) =================
    // P1: q00 reads (12); finish current D1 (A-half1)
    RDA(aLo, arA0, 0);
    RDB(bLo, arB0, 0);
    STG_A(1, 1, koD1);
    WLG(8);
    BAR();
    WLG(0);
    MFQ(aLo, bLo, 0, 0);
    BAR();
    // P2: q01 reads B n2-3 (4); stage next-D0.B0
    RDB(bHi, arB0, 2);
    if (st) STG_B(0, 0, koN0);
    BAR();
    WLG(0);
    MFQ(aLo, bHi, 0, 2);
    BAR();
    // P3: q11 reads A m4-7 (8); stage next-D0.B1
    RDA(aHi, arA0, 4);
    if (st) STG_B(0, 1, koN0);
    BAR();
    WLG(0);
    MFQ(aHi, bHi, 4, 2);
    BAR();
    // P4: q10 (0 reads); stage next-D0.A0; counted vmcnt -> D1 fully landed
    if (st) {
      STG_A(0, 0, koN0);
      WVM(6);
    } else {
      WVM(0);
    }
    BAR();
    MFQ(aHi, bLo, 4, 0);
    BAR();

    // ================= D1 (tile 2i+1) =================
    // P5: q00 reads (12); stage next-D0.A1
    RDA(aLo, arA1, 0);
    RDB(bLo, arB1, 0);
    if (st) STG_A(0, 1, koN0);
    WLG(8);
    BAR();
    WLG(0);
    MFQ(aLo, bLo, 0, 0);
    BAR();
    // P6: q01; stage next-D1.B0
    RDB(bHi, arB1, 2);
    if (st) STG_B(1, 0, koN1);
    BAR();
    WLG(0);
    MFQ(aLo, bHi, 0, 2);
    BAR();
    // P7: q11; stage next-D1.B1
    RDA(aHi, arA1, 4);
    if (st) STG_B(1, 1, koN1);
    BAR();
    WLG(0);
    MFQ(aHi, bHi, 4, 2);
    BAR();
    // P8: q10; stage next-D1.A0; counted vmcnt -> next-D0 fully landed
    if (st) {
      STG_A(1, 0, koN1);
      WVM(6);
    }
    BAR();
    MFQ(aHi, bLo, 4, 0);
    BAR();
  }

  // epilogue: C/D layout col = lane&15, row = (lane>>4)*4 + q
  float* Cp = out + (size_t)p * 33554432UL +
              ((size_t)(brow * 256 + wm * 128 + g * 4)) * 4096 +
              (bcol * 256 + wn * 64 + lrow);
#pragma unroll
  for (int m = 0; m < 8; ++m)
#pragma unroll
    for (int q = 0; q < 4; ++q) {
      float* rp = Cp + (size_t)(m * 16 + q) * 4096;
#pragma unroll
      for (int n = 0; n < 4; ++n) rp[n * 16] = acc[m][n][q];
    }
}

// ---------------------------------------------------------------------------
extern "C" void kernel_launch(void* const* d_in, const int* in_sizes, int n_in,
                              void* d_out, int out_size, void* d_ws,
                              size_t ws_size, hipStream_t stream) {
  const float* x = (const float*)d_in[0];
  const float* wq = (const float*)d_in[1];
  const float* wk = (const float*)d_in[2];
  const float* wv = (const float*)d_in[3];
  const float* qa = (const float*)d_in[4];
  const float* qb = (const float*)d_in[5];
  const float* ka = (const float*)d_in[6];
  const float* kb = (const float*)d_in[7];
  const float* va = (const float*)d_in[8];
  const float* vb = (const float*)d_in[9];

  unsigned short* xb = (unsigned short*)d_ws;  // 67 MB
  unsigned short* wb = xb + 8192UL * 4096UL;   // 100 MB

  cvt_x_kernel<<<16384, 256, 0, stream>>>(x, xb, 8192L * 4096 / 8);
  fold_w_kernel<<<8192, 256, 0, stream>>>(wq, qa, qb, wb);
  fold_w_kernel<<<8192, 256, 0, stream>>>(wk, ka, kb, wb + 16777216UL);
  fold_w_kernel<<<8192, 256, 0, stream>>>(wv, va, vb, wb + 33554432UL);
  gemm_kernel<<<1536, 512, 0, stream>>>(xb, wb, (float*)d_out);
}